// Round 1
// baseline (1131.912 us; speedup 1.0000x reference)
//
#include <hip/hip_runtime.h>

// ---- problem constants (pinned by reference) ----
#define NN    20000      // nodes
#define NE    5000       // hyperedges
#define NNZ_  200000     // incidences
#define DD    6          // sheaf dim d (heads)
#define HH    9          // MLP hidden
#define DHID  54         // DD*HH
#define FIN   256        // input features
#define ODIM  4968       // output features
#define NCAP  64         // node bucket capacity (mean deg 10)
#define ECAP  128        // edge bucket capacity (mean deg 40)

// ---- MFMA GEMM padding ----
#define MPAD  20096      // 157*128 rows (A padded, zero-filled tail)
#define NPAD  4992       // 39*128 cols (W^T padded, zero-filled tail)
#define KP    64         // K padded 54 -> 64 (two 16x16x32 k-steps)

using bfx8   = __attribute__((ext_vector_type(8))) __bf16;
using f32x4t = __attribute__((ext_vector_type(4))) float;

// ---------------------------------------------------------------------------
// proj: row i of `in` (FIN floats) @ lin_w (FIN x 54) + lin_b -> proj row (54)
// also emits per-d mean (9 floats). One 64-thread block per row.
// ---------------------------------------------------------------------------
__global__ __launch_bounds__(64) void proj_kernel(
    const float* __restrict__ in, const float* __restrict__ w,
    const float* __restrict__ b, float* __restrict__ proj_out,
    float* __restrict__ mean_out)
{
    const int i = blockIdx.x;
    const int t = threadIdx.x;
    __shared__ float xrow[FIN];
    __shared__ float prow[DHID];

    // 256 floats = 64 lanes x float4, coalesced
    ((float4*)xrow)[t] = ((const float4*)(in + (size_t)i * FIN))[t];
    __syncthreads();

    if (t < DHID) {
        float acc = b[t];
        #pragma unroll 4
        for (int k = 0; k < FIN; ++k)
            acc += xrow[k] * w[k * DHID + t];
        prow[t] = acc;
        if (proj_out) proj_out[(size_t)i * DHID + t] = acc;
    }
    __syncthreads();
    if (t < HH) {
        float s = 0.f;
        #pragma unroll
        for (int r = 0; r < DD; ++r) s += prow[r * HH + t];
        mean_out[(size_t)i * HH + t] = s * (1.0f / DD);
    }
}

// ---------------------------------------------------------------------------
// Build incidence buckets + degree counts (once per launch; indices static).
// ---------------------------------------------------------------------------
__global__ void fill_kernel(const int* __restrict__ node_idx,
                            const int* __restrict__ edge_idx,
                            int* __restrict__ ncnt, int* __restrict__ ecnt,
                            int* __restrict__ nbuck, int* __restrict__ ebuck)
{
    int nz = blockIdx.x * blockDim.x + threadIdx.x;
    if (nz >= NNZ_) return;
    int n = node_idx[nz], e = edge_idx[nz];
    int p = atomicAdd(&ncnt[n], 1);
    if (p < NCAP) nbuck[n * NCAP + p] = nz;
    int q = atomicAdd(&ecnt[e], 1);
    if (q < ECAP) ebuck[e * ECAP + q] = nz;
}

__global__ void inv_kernel(const int* __restrict__ ncnt, const int* __restrict__ ecnt,
                           float* __restrict__ ninv, float* __restrict__ einv)
{
    int i = blockIdx.x * blockDim.x + threadIdx.x;
    if (i < NN) {
        int c = ncnt[i];
        ninv[i] = (c > 0) ? 1.0f / (float)c : 0.0f;
    }
    int j = i - NN;
    if (j >= 0 && j < NE) {
        int c = ecnt[j];
        einv[j] = (c > 0) ? 1.0f / (float)c : 0.0f;
    }
}

// ---------------------------------------------------------------------------
// Sheaf: per incidence, LN(concat(xm[n], em[e])) @ sheaf_w + b, sigmoid -> alpha[6]
// ---------------------------------------------------------------------------
__global__ void sheaf_kernel(const int* __restrict__ node_idx,
                             const int* __restrict__ edge_idx,
                             const float* __restrict__ xm, const float* __restrict__ em,
                             const float* __restrict__ g, const float* __restrict__ b,
                             const float* __restrict__ w, const float* __restrict__ bb,
                             float* __restrict__ alpha)
{
    int nz = blockIdx.x * blockDim.x + threadIdx.x;
    if (nz >= NNZ_) return;
    float p[18];
    const float* xr = xm + (size_t)node_idx[nz] * HH;
    const float* er = em + (size_t)edge_idx[nz] * HH;
    #pragma unroll
    for (int h = 0; h < HH; ++h) { p[h] = xr[h]; p[HH + h] = er[h]; }

    float mean = 0.f;
    #pragma unroll
    for (int k = 0; k < 18; ++k) mean += p[k];
    mean *= (1.0f / 18.0f);
    float var = 0.f;
    #pragma unroll
    for (int k = 0; k < 18; ++k) { float d = p[k] - mean; var += d * d; }
    var *= (1.0f / 18.0f);
    float rin = rsqrtf(var + 1e-5f);
    #pragma unroll
    for (int k = 0; k < 18; ++k) p[k] = (p[k] - mean) * rin * g[k] + b[k];

    #pragma unroll
    for (int c = 0; c < DD; ++c) {
        float z = bb[c];
        #pragma unroll
        for (int k = 0; k < 18; ++k) z += p[k] * w[k * DD + c];
        alpha[(size_t)nz * DD + c] = 1.0f / (1.0f + expf(-z));
    }
}

// ---------------------------------------------------------------------------
// conv lin: h0 = LN(x) @ W + cb, one thread per expanded row (N*d rows of 9)
// ---------------------------------------------------------------------------
__global__ void conv_lin_kernel(const float* __restrict__ xin,
                                const float* __restrict__ g, const float* __restrict__ b,
                                const float* __restrict__ W, const float* __restrict__ cb,
                                float* __restrict__ h0)
{
    int row = blockIdx.x * blockDim.x + threadIdx.x;
    if (row >= NN * DD) return;
    const float* xr = xin + (size_t)row * HH;
    float v[HH];
    float mean = 0.f;
    #pragma unroll
    for (int k = 0; k < HH; ++k) { v[k] = xr[k]; mean += v[k]; }
    mean *= (1.0f / HH);
    float var = 0.f;
    #pragma unroll
    for (int k = 0; k < HH; ++k) { float d = v[k] - mean; var += d * d; }
    var *= (1.0f / HH);
    float rin = rsqrtf(var + 1e-5f);
    float ln[HH];
    #pragma unroll
    for (int k = 0; k < HH; ++k) ln[k] = (v[k] - mean) * rin * g[k] + b[k];
    #pragma unroll
    for (int j = 0; j < HH; ++j) {
        float s = cb[j];
        #pragma unroll
        for (int k = 0; k < HH; ++k) s += ln[k] * W[k * HH + j];
        h0[(size_t)row * HH + j] = s;
    }
}

// ---------------------------------------------------------------------------
// node -> edge aggregation: m[e*6+rd][h] = einv[e] * sum alpha * h0[n*6+rd][h]
// ---------------------------------------------------------------------------
__global__ void edge_agg_kernel(const int* __restrict__ ecnt, const int* __restrict__ ebuck,
                                const int* __restrict__ node_idx,
                                const float* __restrict__ alpha,
                                const float* __restrict__ h0,
                                const float* __restrict__ einv,
                                float* __restrict__ m)
{
    int t = blockIdx.x * blockDim.x + threadIdx.x;
    if (t >= NE * DD * HH) return;
    int h = t % HH;
    int er = t / HH;          // e*6+rd
    int e = er / DD;
    int rd = er - e * DD;
    int cnt = ecnt[e];
    if (cnt > ECAP) cnt = ECAP;
    const int* bl = ebuck + (size_t)e * ECAP;
    float s = 0.f;
    for (int j = 0; j < cnt; ++j) {
        int nz = bl[j];
        float a = alpha[(size_t)nz * DD + rd];
        int n = node_idx[nz];
        s += a * h0[((size_t)n * DD + rd) * HH + h];
    }
    m[(size_t)t] = s * einv[e];
}

// ---------------------------------------------------------------------------
// edge -> node aggregation fused with residual+bias+activation
// ---------------------------------------------------------------------------
__global__ void node_agg_kernel(const int* __restrict__ ncnt, const int* __restrict__ nbuck,
                                const int* __restrict__ edge_idx,
                                const float* __restrict__ alpha,
                                const float* __restrict__ m,
                                const float* __restrict__ ninv,
                                const float* __restrict__ h0,
                                const float* __restrict__ cbias,
                                float* __restrict__ xout, int do_elu)
{
    int t = blockIdx.x * blockDim.x + threadIdx.x;
    if (t >= NN * DD * HH) return;
    int h = t % HH;
    int row = t / HH;         // n*6+rd
    int n = row / DD;
    int rd = row - n * DD;
    int cnt = ncnt[n];
    if (cnt > NCAP) cnt = NCAP;
    const int* bl = nbuck + (size_t)n * NCAP;
    float s = 0.f;
    for (int j = 0; j < cnt; ++j) {
        int nz = bl[j];
        float a = alpha[(size_t)nz * DD + rd];
        int e = edge_idx[nz];
        s += a * m[((size_t)e * DD + rd) * HH + h];
    }
    float v = s * ninv[n] + h0[t] + cbias[h];
    if (do_elu) v = (v > 0.f) ? v : (expf(v) - 1.0f);
    xout[t] = v;
}

// ---------------------------------------------------------------------------
// bf16 split helpers: v = hi + lo with |err| ~ 2^-16 |v|
// ---------------------------------------------------------------------------
__device__ inline void bf16_split(float v, unsigned short& hi, unsigned short& lo)
{
    unsigned u = __float_as_uint(v);
    unsigned r = (u + 0x7FFFu + ((u >> 16) & 1u)) >> 16;   // RNE to bf16
    hi = (unsigned short)r;
    float hf = __uint_as_float(r << 16);
    float l = v - hf;                                      // exact (Sterbenz)
    unsigned ul = __float_as_uint(l);
    unsigned rl = (ul + 0x7FFFu + ((ul >> 16) & 1u)) >> 16;
    lo = (unsigned short)rl;
}

// A: xin[NN][54] fp32 -> Ahi/Alo [MPAD][64] bf16 (zero pad rows/k)
__global__ __launch_bounds__(256) void convA_kernel(const float* __restrict__ x,
        unsigned short* __restrict__ ahi, unsigned short* __restrict__ alo)
{
    int id = blockIdx.x * 256 + threadIdx.x;
    if (id >= MPAD * KP) return;
    int r = id >> 6, k = id & 63;
    float v = (r < NN && k < DHID) ? x[(size_t)r * DHID + k] : 0.f;
    unsigned short h, l;
    bf16_split(v, h, l);
    ahi[id] = h; alo[id] = l;
}

// W: lin2_w[54][4968] fp32 -> Whi/Wlo [NPAD][64] bf16 (transposed, zero pad)
__global__ __launch_bounds__(256) void convW_kernel(const float* __restrict__ w,
        unsigned short* __restrict__ whi, unsigned short* __restrict__ wlo)
{
    int id = blockIdx.x * 256 + threadIdx.x;
    if (id >= NPAD * KP) return;
    int n = id >> 6, k = id & 63;
    float v = (n < ODIM && k < DHID) ? w[(size_t)k * ODIM + n] : 0.f;
    unsigned short h, l;
    bf16_split(v, h, l);
    whi[id] = h; wlo[id] = l;
}

// ---------------------------------------------------------------------------
// final GEMM via split-bf16 MFMA: C = A @ W + bias, fp32-comparable accuracy.
// grid = (NPAD/128, MPAD/128), 256 threads (4 waves). Each wave: 32x128 tile
// = 2x8 MFMA tiles of 16x16, K=64 in two 16x16x32 k-steps, 3 split terms.
// No LDS, no barriers: fragments loaded straight from L2-resident operands
// (A/W layout is k-contiguous per row, matching the MFMA fragment layout:
//  lane l holds row/col (l&15), k = (l>>4)*8 .. +8).
// ---------------------------------------------------------------------------
__global__ __launch_bounds__(256) void gemm_lin2_mfma(
    const unsigned short* __restrict__ Ahi, const unsigned short* __restrict__ Alo,
    const unsigned short* __restrict__ Whi, const unsigned short* __restrict__ Wlo,
    const float* __restrict__ bias, float* __restrict__ C)
{
    const int wid  = threadIdx.x >> 6;     // wave 0..3 -> 32-row strip
    const int lane = threadIdx.x & 63;
    const int lr   = lane & 15;            // row (A) / col (B,C) within tile
    const int kg   = lane >> 4;            // k-group 0..3 (k offset kg*8)

    const int row0 = blockIdx.y * 128 + wid * 32;
    const int col0 = blockIdx.x * 128;

    // A fragments: [mtile][kstep][split], 8 x bfx8 = 32 VGPR, live whole kernel
    bfx8 a[2][2][2];
    #pragma unroll
    for (int m = 0; m < 2; ++m) {
        size_t ab = (size_t)(row0 + m * 16 + lr) * KP + kg * 8;
        a[m][0][0] = *(const bfx8*)(Ahi + ab);
        a[m][1][0] = *(const bfx8*)(Ahi + ab + 32);
        a[m][0][1] = *(const bfx8*)(Alo + ab);
        a[m][1][1] = *(const bfx8*)(Alo + ab + 32);
    }

    f32x4t acc[2][8];
    #pragma unroll
    for (int m = 0; m < 2; ++m)
        #pragma unroll
        for (int nt = 0; nt < 8; ++nt)
            #pragma unroll
            for (int r = 0; r < 4; ++r) acc[m][nt][r] = 0.f;

    #pragma unroll 2
    for (int nt = 0; nt < 8; ++nt) {
        size_t wb = (size_t)(col0 + nt * 16 + lr) * KP + kg * 8;
        bfx8 b00 = *(const bfx8*)(Whi + wb);        // kstep0 hi
        bfx8 b10 = *(const bfx8*)(Whi + wb + 32);   // kstep1 hi
        bfx8 b01 = *(const bfx8*)(Wlo + wb);        // kstep0 lo
        bfx8 b11 = *(const bfx8*)(Wlo + wb + 32);   // kstep1 lo
        #pragma unroll
        for (int m = 0; m < 2; ++m) {
            // hi*hi + hi*lo + lo*hi per k-step (error ~ 2^-16 relative)
            acc[m][nt] = __builtin_amdgcn_mfma_f32_16x16x32_bf16(a[m][0][0], b00, acc[m][nt], 0, 0, 0);
            acc[m][nt] = __builtin_amdgcn_mfma_f32_16x16x32_bf16(a[m][1][0], b10, acc[m][nt], 0, 0, 0);
            acc[m][nt] = __builtin_amdgcn_mfma_f32_16x16x32_bf16(a[m][0][0], b01, acc[m][nt], 0, 0, 0);
            acc[m][nt] = __builtin_amdgcn_mfma_f32_16x16x32_bf16(a[m][1][0], b11, acc[m][nt], 0, 0, 0);
            acc[m][nt] = __builtin_amdgcn_mfma_f32_16x16x32_bf16(a[m][0][1], b00, acc[m][nt], 0, 0, 0);
            acc[m][nt] = __builtin_amdgcn_mfma_f32_16x16x32_bf16(a[m][1][1], b10, acc[m][nt], 0, 0, 0);
        }
    }

    // epilogue: C/D layout col = lane&15, row = (lane>>4)*4 + reg
    #pragma unroll
    for (int nt = 0; nt < 8; ++nt) {
        int col = col0 + nt * 16 + lr;
        if (col >= ODIM) continue;
        float bv = bias[col];
        #pragma unroll
        for (int m = 0; m < 2; ++m) {
            int rbase = row0 + m * 16 + kg * 4;
            #pragma unroll
            for (int r = 0; r < 4; ++r) {
                int row = rbase + r;
                if (row < NN)
                    C[(size_t)row * ODIM + col] = acc[m][nt][r] + bv;
            }
        }
    }
}

// ---------------------------------------------------------------------------
extern "C" void kernel_launch(void* const* d_in, const int* in_sizes, int n_in,
                              void* d_out, int out_size, void* d_ws, size_t ws_size,
                              hipStream_t stream)
{
    const float* x        = (const float*)d_in[0];
    const float* ha       = (const float*)d_in[1];
    const int*   node_idx = (const int*)d_in[2];
    const int*   edge_idx = (const int*)d_in[3];
    const float* lin_w    = (const float*)d_in[4];
    const float* lin_b    = (const float*)d_in[5];
    const float* sln_g    = (const float*)d_in[6];
    const float* sln_b    = (const float*)d_in[7];
    const float* sheaf_w  = (const float*)d_in[8];
    const float* sheaf_b  = (const float*)d_in[9];
    const float* cln_g    = (const float*)d_in[10];
    const float* cln_b    = (const float*)d_in[11];
    const float* conv_w   = (const float*)d_in[12];
    const float* conv_b   = (const float*)d_in[13];
    const float* conv_bias= (const float*)d_in[14];
    const float* lin2_w   = (const float*)d_in[15];
    const float* lin2_b   = (const float*)d_in[16];
    float* out = (float*)d_out;

    // ---- workspace layout (floats then ints), ~27.7 MB ----
    float* ws = (float*)d_ws;
    float* xp    = ws;                          // NN*54
    float* xb    = xp + (size_t)NN * DHID;      // NN*54
    float* h0    = xb + (size_t)NN * DHID;      // NN*54
    float* xm    = h0 + (size_t)NN * DHID;      // NN*9
    float* em    = xm + (size_t)NN * HH;        // NE*9
    float* alpha = em + (size_t)NE * HH;        // NNZ*6
    float* mbuf  = alpha + (size_t)NNZ_ * DD;   // NE*54
    float* ninv  = mbuf + (size_t)NE * DHID;    // NN
    float* einv  = ninv + NN;                   // NE
    int* ncnt  = (int*)(einv + NE);             // NN
    int* ecnt  = ncnt + NN;                     // NE
    int* nbuck = ecnt + NE;                     // NN*NCAP
    int* ebuck = nbuck + (size_t)NN * NCAP;     // NE*ECAP

    // bf16-split GEMM operands, aliased onto buffers dead by GEMM time:
    //  - A (2*MPAD*64*2B = 5.14 MB) over h0+xm+em (5.22 MB, dead after layer 2)
    //  - W (2*NPAD*64*2B = 1.28 MB) over alpha (4.8 MB, dead after layer 2)
    unsigned short* Ahi = (unsigned short*)h0;
    unsigned short* Alo = Ahi + (size_t)MPAD * KP;
    unsigned short* Whi = (unsigned short*)alpha;
    unsigned short* Wlo = Whi + (size_t)NPAD * KP;

    // zero degree counters (ws is poisoned before every call)
    hipMemsetAsync(ncnt, 0, (NN + NE) * sizeof(int), stream);

    // projections + per-d means
    proj_kernel<<<NN, 64, 0, stream>>>(x, lin_w, lin_b, xp, xm);
    proj_kernel<<<NE, 64, 0, stream>>>(ha, lin_w, lin_b, nullptr, em);

    // incidence buckets + degrees
    fill_kernel<<<(NNZ_ + 255) / 256, 256, 0, stream>>>(node_idx, edge_idx,
                                                        ncnt, ecnt, nbuck, ebuck);
    inv_kernel<<<(NN + NE + 255) / 256, 256, 0, stream>>>(ncnt, ecnt, ninv, einv);

    // sheaf attributes (static across layers)
    sheaf_kernel<<<(NNZ_ + 255) / 256, 256, 0, stream>>>(
        node_idx, edge_idx, xm, em, sln_g, sln_b, sheaf_w, sheaf_b, alpha);

    // conv layers
    const float* xin = xp;
    float* xout = xb;
    for (int l = 0; l < 2; ++l) {
        conv_lin_kernel<<<(NN * DD + 255) / 256, 256, 0, stream>>>(
            xin, cln_g + l * HH, cln_b + l * HH, conv_w + l * HH * HH,
            conv_b + l * HH, h0);
        edge_agg_kernel<<<(NE * DD * HH + 255) / 256, 256, 0, stream>>>(
            ecnt, ebuck, node_idx, alpha, h0, einv, mbuf);
        node_agg_kernel<<<(NN * DD * HH + 255) / 256, 256, 0, stream>>>(
            ncnt, nbuck, edge_idx, alpha, mbuf, ninv, h0,
            conv_bias + l * HH, xout, (l == 0) ? 1 : 0);
        const float* tmp = xin; xin = xout; xout = (float*)tmp;
    }
    // xin == xp here (2 swaps); h0/xm/em/alpha/mbuf now dead -> safe to alias.

    // split-convert operands for the MFMA GEMM
    convA_kernel<<<(MPAD * KP) / 256, 256, 0, stream>>>(xin, Ahi, Alo);
    convW_kernel<<<(NPAD * KP) / 256, 256, 0, stream>>>(lin2_w, Whi, Wlo);

    // final GEMM: C[20000,4968] = A @ W + bias via 3-term split-bf16 MFMA
    dim3 grid(NPAD / 128, MPAD / 128);
    gemm_lin2_mfma<<<grid, 256, 0, stream>>>(Ahi, Alo, Whi, Wlo, lin2_b, out);
}

// Round 3
// 952.721 us; speedup vs baseline: 1.1881x; 1.1881x over previous
//
#include <hip/hip_runtime.h>

// ---- problem constants (pinned by reference) ----
#define NN    20000      // nodes
#define NE    5000       // hyperedges
#define NNZ_  200000     // incidences
#define DD    6          // sheaf dim d (heads)
#define HH    9          // MLP hidden
#define DHID  54         // DD*HH
#define FIN   256        // input features
#define ODIM  4968       // output features
#define NCAP  64         // node bucket capacity (mean deg 10)
#define ECAP  128        // edge bucket capacity (mean deg 40)

// ---- MFMA GEMM padding ----
#define MPAD  20096      // 157*128 rows (A padded, zero-filled tail)
#define NPAD  4992       // 39*128 cols (W^T padded, zero-filled tail)
#define KP    64         // K padded 54 -> 64 (two 16x16x32 k-steps)

using bfx8   = __attribute__((ext_vector_type(8))) __bf16;
using f32x4t = __attribute__((ext_vector_type(4))) float;

// ---------------------------------------------------------------------------
// proj: row i of `in` (FIN floats) @ lin_w (FIN x 54) + lin_b -> proj row (54)
// also emits per-d mean (9 floats). One 64-thread block per row.
// ---------------------------------------------------------------------------
__global__ __launch_bounds__(64) void proj_kernel(
    const float* __restrict__ in, const float* __restrict__ w,
    const float* __restrict__ b, float* __restrict__ proj_out,
    float* __restrict__ mean_out)
{
    const int i = blockIdx.x;
    const int t = threadIdx.x;
    __shared__ float xrow[FIN];
    __shared__ float prow[DHID];

    // 256 floats = 64 lanes x float4, coalesced
    ((float4*)xrow)[t] = ((const float4*)(in + (size_t)i * FIN))[t];
    __syncthreads();

    if (t < DHID) {
        float acc = b[t];
        #pragma unroll 4
        for (int k = 0; k < FIN; ++k)
            acc += xrow[k] * w[k * DHID + t];
        prow[t] = acc;
        if (proj_out) proj_out[(size_t)i * DHID + t] = acc;
    }
    __syncthreads();
    if (t < HH) {
        float s = 0.f;
        #pragma unroll
        for (int r = 0; r < DD; ++r) s += prow[r * HH + t];
        mean_out[(size_t)i * HH + t] = s * (1.0f / DD);
    }
}

// ---------------------------------------------------------------------------
// Build incidence buckets + degree counts (once per launch; indices static).
// ---------------------------------------------------------------------------
__global__ void fill_kernel(const int* __restrict__ node_idx,
                            const int* __restrict__ edge_idx,
                            int* __restrict__ ncnt, int* __restrict__ ecnt,
                            int* __restrict__ nbuck, int* __restrict__ ebuck)
{
    int nz = blockIdx.x * blockDim.x + threadIdx.x;
    if (nz >= NNZ_) return;
    int n = node_idx[nz], e = edge_idx[nz];
    int p = atomicAdd(&ncnt[n], 1);
    if (p < NCAP) nbuck[n * NCAP + p] = nz;
    int q = atomicAdd(&ecnt[e], 1);
    if (q < ECAP) ebuck[e * ECAP + q] = nz;
}

__global__ void inv_kernel(const int* __restrict__ ncnt, const int* __restrict__ ecnt,
                           float* __restrict__ ninv, float* __restrict__ einv)
{
    int i = blockIdx.x * blockDim.x + threadIdx.x;
    if (i < NN) {
        int c = ncnt[i];
        ninv[i] = (c > 0) ? 1.0f / (float)c : 0.0f;
    }
    int j = i - NN;
    if (j >= 0 && j < NE) {
        int c = ecnt[j];
        einv[j] = (c > 0) ? 1.0f / (float)c : 0.0f;
    }
}

// ---------------------------------------------------------------------------
// Sheaf: per incidence, LN(concat(xm[n], em[e])) @ sheaf_w + b, sigmoid -> alpha[6]
// ---------------------------------------------------------------------------
__global__ void sheaf_kernel(const int* __restrict__ node_idx,
                             const int* __restrict__ edge_idx,
                             const float* __restrict__ xm, const float* __restrict__ em,
                             const float* __restrict__ g, const float* __restrict__ b,
                             const float* __restrict__ w, const float* __restrict__ bb,
                             float* __restrict__ alpha)
{
    int nz = blockIdx.x * blockDim.x + threadIdx.x;
    if (nz >= NNZ_) return;
    float p[18];
    const float* xr = xm + (size_t)node_idx[nz] * HH;
    const float* er = em + (size_t)edge_idx[nz] * HH;
    #pragma unroll
    for (int h = 0; h < HH; ++h) { p[h] = xr[h]; p[HH + h] = er[h]; }

    float mean = 0.f;
    #pragma unroll
    for (int k = 0; k < 18; ++k) mean += p[k];
    mean *= (1.0f / 18.0f);
    float var = 0.f;
    #pragma unroll
    for (int k = 0; k < 18; ++k) { float d = p[k] - mean; var += d * d; }
    var *= (1.0f / 18.0f);
    float rin = rsqrtf(var + 1e-5f);
    #pragma unroll
    for (int k = 0; k < 18; ++k) p[k] = (p[k] - mean) * rin * g[k] + b[k];

    #pragma unroll
    for (int c = 0; c < DD; ++c) {
        float z = bb[c];
        #pragma unroll
        for (int k = 0; k < 18; ++k) z += p[k] * w[k * DD + c];
        alpha[(size_t)nz * DD + c] = 1.0f / (1.0f + expf(-z));
    }
}

// ---------------------------------------------------------------------------
// conv lin: h0 = LN(x) @ W + cb, one thread per expanded row (N*d rows of 9)
// ---------------------------------------------------------------------------
__global__ void conv_lin_kernel(const float* __restrict__ xin,
                                const float* __restrict__ g, const float* __restrict__ b,
                                const float* __restrict__ W, const float* __restrict__ cb,
                                float* __restrict__ h0)
{
    int row = blockIdx.x * blockDim.x + threadIdx.x;
    if (row >= NN * DD) return;
    const float* xr = xin + (size_t)row * HH;
    float v[HH];
    float mean = 0.f;
    #pragma unroll
    for (int k = 0; k < HH; ++k) { v[k] = xr[k]; mean += v[k]; }
    mean *= (1.0f / HH);
    float var = 0.f;
    #pragma unroll
    for (int k = 0; k < HH; ++k) { float d = v[k] - mean; var += d * d; }
    var *= (1.0f / HH);
    float rin = rsqrtf(var + 1e-5f);
    float ln[HH];
    #pragma unroll
    for (int k = 0; k < HH; ++k) ln[k] = (v[k] - mean) * rin * g[k] + b[k];
    #pragma unroll
    for (int j = 0; j < HH; ++j) {
        float s = cb[j];
        #pragma unroll
        for (int k = 0; k < HH; ++k) s += ln[k] * W[k * HH + j];
        h0[(size_t)row * HH + j] = s;
    }
}

// ---------------------------------------------------------------------------
// node -> edge aggregation: m[e*6+rd][h] = einv[e] * sum alpha * h0[n*6+rd][h]
// ---------------------------------------------------------------------------
__global__ void edge_agg_kernel(const int* __restrict__ ecnt, const int* __restrict__ ebuck,
                                const int* __restrict__ node_idx,
                                const float* __restrict__ alpha,
                                const float* __restrict__ h0,
                                const float* __restrict__ einv,
                                float* __restrict__ m)
{
    int t = blockIdx.x * blockDim.x + threadIdx.x;
    if (t >= NE * DD * HH) return;
    int h = t % HH;
    int er = t / HH;          // e*6+rd
    int e = er / DD;
    int rd = er - e * DD;
    int cnt = ecnt[e];
    if (cnt > ECAP) cnt = ECAP;
    const int* bl = ebuck + (size_t)e * ECAP;
    float s = 0.f;
    for (int j = 0; j < cnt; ++j) {
        int nz = bl[j];
        float a = alpha[(size_t)nz * DD + rd];
        int n = node_idx[nz];
        s += a * h0[((size_t)n * DD + rd) * HH + h];
    }
    m[(size_t)t] = s * einv[e];
}

// ---------------------------------------------------------------------------
// edge -> node aggregation fused with residual+bias+activation
// ---------------------------------------------------------------------------
__global__ void node_agg_kernel(const int* __restrict__ ncnt, const int* __restrict__ nbuck,
                                const int* __restrict__ edge_idx,
                                const float* __restrict__ alpha,
                                const float* __restrict__ m,
                                const float* __restrict__ ninv,
                                const float* __restrict__ h0,
                                const float* __restrict__ cbias,
                                float* __restrict__ xout, int do_elu)
{
    int t = blockIdx.x * blockDim.x + threadIdx.x;
    if (t >= NN * DD * HH) return;
    int h = t % HH;
    int row = t / HH;         // n*6+rd
    int n = row / DD;
    int rd = row - n * DD;
    int cnt = ncnt[n];
    if (cnt > NCAP) cnt = NCAP;
    const int* bl = nbuck + (size_t)n * NCAP;
    float s = 0.f;
    for (int j = 0; j < cnt; ++j) {
        int nz = bl[j];
        float a = alpha[(size_t)nz * DD + rd];
        int e = edge_idx[nz];
        s += a * m[((size_t)e * DD + rd) * HH + h];
    }
    float v = s * ninv[n] + h0[t] + cbias[h];
    if (do_elu) v = (v > 0.f) ? v : (expf(v) - 1.0f);
    xout[t] = v;
}

// ---------------------------------------------------------------------------
// bf16 split helpers: v = hi + lo with |err| ~ 2^-16 |v|
// ---------------------------------------------------------------------------
__device__ inline void bf16_split(float v, unsigned short& hi, unsigned short& lo)
{
    unsigned u = __float_as_uint(v);
    unsigned r = (u + 0x7FFFu + ((u >> 16) & 1u)) >> 16;   // RNE to bf16
    hi = (unsigned short)r;
    float hf = __uint_as_float(r << 16);
    float l = v - hf;                                      // exact (Sterbenz)
    unsigned ul = __float_as_uint(l);
    unsigned rl = (ul + 0x7FFFu + ((ul >> 16) & 1u)) >> 16;
    lo = (unsigned short)rl;
}

// A: xin[NN][54] fp32 -> Ahi/Alo [MPAD][64] bf16 (zero pad rows/k)
__global__ __launch_bounds__(256) void convA_kernel(const float* __restrict__ x,
        unsigned short* __restrict__ ahi, unsigned short* __restrict__ alo)
{
    int id = blockIdx.x * 256 + threadIdx.x;
    if (id >= MPAD * KP) return;
    int r = id >> 6, k = id & 63;
    float v = (r < NN && k < DHID) ? x[(size_t)r * DHID + k] : 0.f;
    unsigned short h, l;
    bf16_split(v, h, l);
    ahi[id] = h; alo[id] = l;
}

// W: lin2_w[54][4968] fp32 -> Whi/Wlo [NPAD][64] bf16 (transposed, zero pad)
__global__ __launch_bounds__(256) void convW_kernel(const float* __restrict__ w,
        unsigned short* __restrict__ whi, unsigned short* __restrict__ wlo)
{
    int id = blockIdx.x * 256 + threadIdx.x;
    if (id >= NPAD * KP) return;
    int n = id >> 6, k = id & 63;
    float v = (n < ODIM && k < DHID) ? w[(size_t)k * ODIM + n] : 0.f;
    unsigned short h, l;
    bf16_split(v, h, l);
    whi[id] = h; wlo[id] = l;
}

// ---------------------------------------------------------------------------
// final GEMM via split-bf16 MFMA: C = A @ W + bias, fp32-comparable accuracy.
// grid = (NPAD/128, MPAD/128), 256 threads (4 waves). Each wave: 32x128 tile
// = 2x8 MFMA tiles of 16x16, K=64 in two 16x16x32 k-steps, 3 split terms.
// Main loop: no LDS, no barriers (operands L2-resident, fragments loaded
// straight from global; A/W rows are k-contiguous = exactly one 128B line).
// Epilogue: wave-private LDS transpose so every C store is a full-line
// contiguous float4 burst (round-1 lesson: MFMA-layout scalar stores caused
// 3x write amplification + RMW fetches -> 1.75 GB HBM traffic).
// ---------------------------------------------------------------------------
__global__ __launch_bounds__(256) void gemm_lin2_mfma(
    const unsigned short* __restrict__ Ahi, const unsigned short* __restrict__ Alo,
    const unsigned short* __restrict__ Whi, const unsigned short* __restrict__ Wlo,
    const float* __restrict__ bias, float* __restrict__ C)
{
    const int wid  = threadIdx.x >> 6;     // wave 0..3 -> 32-row strip
    const int lane = threadIdx.x & 63;
    const int lr   = lane & 15;            // row (A) / col (B,C) within tile
    const int kg   = lane >> 4;            // k-group 0..3 (k offset kg*8)

    const int row0 = blockIdx.y * 128 + wid * 32;
    const int col0 = blockIdx.x * 128;

    // wave-private epilogue staging: 16 rows x 128 cols (+4 pad) per wave
    __shared__ float lds[4][16][132];

    // A fragments: [mtile][kstep][split], 8 x bfx8 = 32 VGPR, live whole kernel
    bfx8 a[2][2][2];
    #pragma unroll
    for (int m = 0; m < 2; ++m) {
        size_t ab = (size_t)(row0 + m * 16 + lr) * KP + kg * 8;
        a[m][0][0] = *(const bfx8*)(Ahi + ab);
        a[m][1][0] = *(const bfx8*)(Ahi + ab + 32);
        a[m][0][1] = *(const bfx8*)(Alo + ab);
        a[m][1][1] = *(const bfx8*)(Alo + ab + 32);
    }

    f32x4t acc[2][8];
    #pragma unroll
    for (int m = 0; m < 2; ++m)
        #pragma unroll
        for (int nt = 0; nt < 8; ++nt)
            #pragma unroll
            for (int r = 0; r < 4; ++r) acc[m][nt][r] = 0.f;

    #pragma unroll 2
    for (int nt = 0; nt < 8; ++nt) {
        size_t wb = (size_t)(col0 + nt * 16 + lr) * KP + kg * 8;
        bfx8 b00 = *(const bfx8*)(Whi + wb);        // kstep0 hi
        bfx8 b10 = *(const bfx8*)(Whi + wb + 32);   // kstep1 hi
        bfx8 b01 = *(const bfx8*)(Wlo + wb);        // kstep0 lo
        bfx8 b11 = *(const bfx8*)(Wlo + wb + 32);   // kstep1 lo
        #pragma unroll
        for (int m = 0; m < 2; ++m) {
            // hi*hi + hi*lo + lo*hi per k-step (error ~ 2^-16 relative)
            acc[m][nt] = __builtin_amdgcn_mfma_f32_16x16x32_bf16(a[m][0][0], b00, acc[m][nt], 0, 0, 0);
            acc[m][nt] = __builtin_amdgcn_mfma_f32_16x16x32_bf16(a[m][1][0], b10, acc[m][nt], 0, 0, 0);
            acc[m][nt] = __builtin_amdgcn_mfma_f32_16x16x32_bf16(a[m][0][0], b01, acc[m][nt], 0, 0, 0);
            acc[m][nt] = __builtin_amdgcn_mfma_f32_16x16x32_bf16(a[m][1][0], b11, acc[m][nt], 0, 0, 0);
            acc[m][nt] = __builtin_amdgcn_mfma_f32_16x16x32_bf16(a[m][0][1], b00, acc[m][nt], 0, 0, 0);
            acc[m][nt] = __builtin_amdgcn_mfma_f32_16x16x32_bf16(a[m][1][1], b10, acc[m][nt], 0, 0, 0);
        }
    }

    // ---- epilogue: LDS transpose from MFMA layout to row-major bursts ----
    // MFMA C/D layout: col = lane&15 (lr), row = (lane>>4)*4 + reg (kg*4+r).
    const int half = lane >> 5;        // 0/1: which of 2 rows this lane stores
    const int cq   = lane & 31;        // col quad index 0..31

    #pragma unroll
    for (int m = 0; m < 2; ++m) {
        // stage m-tile (16x128) into wave-private LDS
        #pragma unroll
        for (int nt = 0; nt < 8; ++nt)
            #pragma unroll
            for (int r = 0; r < 4; ++r)
                lds[wid][kg * 4 + r][nt * 16 + lr] = acc[m][nt][r];

        // read back row-major: 8 iters x (2 rows x 512B contiguous) stores
        #pragma unroll
        for (int it = 0; it < 8; ++it) {
            int rr  = it * 2 + half;
            int row = row0 + m * 16 + rr;
            int col = col0 + cq * 4;
            f32x4t v = *(const f32x4t*)&lds[wid][rr][cq * 4];
            if (row < NN && col < ODIM) {       // ODIM%4==0: whole quad in/out
                f32x4t bv = *(const f32x4t*)&bias[col];
                v += bv;
                __builtin_nontemporal_store(v, (f32x4t*)&C[(size_t)row * ODIM + col]);
            }
        }
    }
}

// ---------------------------------------------------------------------------
extern "C" void kernel_launch(void* const* d_in, const int* in_sizes, int n_in,
                              void* d_out, int out_size, void* d_ws, size_t ws_size,
                              hipStream_t stream)
{
    const float* x        = (const float*)d_in[0];
    const float* ha       = (const float*)d_in[1];
    const int*   node_idx = (const int*)d_in[2];
    const int*   edge_idx = (const int*)d_in[3];
    const float* lin_w    = (const float*)d_in[4];
    const float* lin_b    = (const float*)d_in[5];
    const float* sln_g    = (const float*)d_in[6];
    const float* sln_b    = (const float*)d_in[7];
    const float* sheaf_w  = (const float*)d_in[8];
    const float* sheaf_b  = (const float*)d_in[9];
    const float* cln_g    = (const float*)d_in[10];
    const float* cln_b    = (const float*)d_in[11];
    const float* conv_w   = (const float*)d_in[12];
    const float* conv_b   = (const float*)d_in[13];
    const float* conv_bias= (const float*)d_in[14];
    const float* lin2_w   = (const float*)d_in[15];
    const float* lin2_b   = (const float*)d_in[16];
    float* out = (float*)d_out;

    // ---- workspace layout (floats then ints), ~27.7 MB ----
    float* ws = (float*)d_ws;
    float* xp    = ws;                          // NN*54
    float* xb    = xp + (size_t)NN * DHID;      // NN*54
    float* h0    = xb + (size_t)NN * DHID;      // NN*54
    float* xm    = h0 + (size_t)NN * DHID;      // NN*9
    float* em    = xm + (size_t)NN * HH;        // NE*9
    float* alpha = em + (size_t)NE * HH;        // NNZ*6
    float* mbuf  = alpha + (size_t)NNZ_ * DD;   // NE*54
    float* ninv  = mbuf + (size_t)NE * DHID;    // NN
    float* einv  = ninv + NN;                   // NE
    int* ncnt  = (int*)(einv + NE);             // NN
    int* ecnt  = ncnt + NN;                     // NE
    int* nbuck = ecnt + NE;                     // NN*NCAP
    int* ebuck = nbuck + (size_t)NN * NCAP;     // NE*ECAP

    // bf16-split GEMM operands, aliased onto buffers dead by GEMM time:
    //  - A (2*MPAD*64*2B = 5.14 MB) over h0+xm+em (5.22 MB, dead after layer 2)
    //  - W (2*NPAD*64*2B = 1.28 MB) over alpha (4.8 MB, dead after layer 2)
    unsigned short* Ahi = (unsigned short*)h0;
    unsigned short* Alo = Ahi + (size_t)MPAD * KP;
    unsigned short* Whi = (unsigned short*)alpha;
    unsigned short* Wlo = Whi + (size_t)NPAD * KP;

    // zero degree counters (ws is poisoned before every call)
    hipMemsetAsync(ncnt, 0, (NN + NE) * sizeof(int), stream);

    // projections + per-d means
    proj_kernel<<<NN, 64, 0, stream>>>(x, lin_w, lin_b, xp, xm);
    proj_kernel<<<NE, 64, 0, stream>>>(ha, lin_w, lin_b, nullptr, em);

    // incidence buckets + degrees
    fill_kernel<<<(NNZ_ + 255) / 256, 256, 0, stream>>>(node_idx, edge_idx,
                                                        ncnt, ecnt, nbuck, ebuck);
    inv_kernel<<<(NN + NE + 255) / 256, 256, 0, stream>>>(ncnt, ecnt, ninv, einv);

    // sheaf attributes (static across layers)
    sheaf_kernel<<<(NNZ_ + 255) / 256, 256, 0, stream>>>(
        node_idx, edge_idx, xm, em, sln_g, sln_b, sheaf_w, sheaf_b, alpha);

    // conv layers
    const float* xin = xp;
    float* xout = xb;
    for (int l = 0; l < 2; ++l) {
        conv_lin_kernel<<<(NN * DD + 255) / 256, 256, 0, stream>>>(
            xin, cln_g + l * HH, cln_b + l * HH, conv_w + l * HH * HH,
            conv_b + l * HH, h0);
        edge_agg_kernel<<<(NE * DD * HH + 255) / 256, 256, 0, stream>>>(
            ecnt, ebuck, node_idx, alpha, h0, einv, mbuf);
        node_agg_kernel<<<(NN * DD * HH + 255) / 256, 256, 0, stream>>>(
            ncnt, nbuck, edge_idx, alpha, mbuf, ninv, h0,
            conv_bias + l * HH, xout, (l == 0) ? 1 : 0);
        const float* tmp = xin; xin = xout; xout = (float*)tmp;
    }
    // xin == xp here (2 swaps); h0/xm/em/alpha/mbuf now dead -> safe to alias.

    // split-convert operands for the MFMA GEMM
    convA_kernel<<<(MPAD * KP) / 256, 256, 0, stream>>>(xin, Ahi, Alo);
    convW_kernel<<<(NPAD * KP) / 256, 256, 0, stream>>>(lin2_w, Whi, Wlo);

    // final GEMM: C[20000,4968] = A @ W + bias via 3-term split-bf16 MFMA
    dim3 grid(NPAD / 128, MPAD / 128);
    gemm_lin2_mfma<<<grid, 256, 0, stream>>>(Ahi, Alo, Whi, Wlo, lin2_b, out);
}